// Round 1
// baseline (1170.251 us; speedup 1.0000x reference)
//
#include <hip/hip_runtime.h>
#include <hip/hip_bf16.h>

typedef __bf16 bf16x8 __attribute__((ext_vector_type(8)));
typedef float  f32x4  __attribute__((ext_vector_type(4)));

__device__ __forceinline__ float sigmoidf_(float x){ return 1.f/(1.f+__expf(-x)); }
__device__ __forceinline__ float tanhf_(float x){
  float ax = fabsf(x);
  float e = __expf(-2.f*ax);
  float t = (1.f - e)/(1.f + e);
  return copysignf(t, x);
}

// float <-> order-preserving unsigned for atomicMax on floats
__device__ __forceinline__ unsigned encf(float f){
  unsigned u = __float_as_uint(f);
  return (u & 0x80000000u) ? ~u : (u | 0x80000000u);
}
__device__ __forceinline__ float decf(unsigned u){
  return __uint_as_float((u & 0x80000000u) ? (u ^ 0x80000000u) : ~u);
}

// LDS swizzles: XOR row-low-bits into 16B-slot bits (G4 fix for power-of-2 row strides)
__device__ __forceinline__ int swzA(int row, int byteoff){ return ((row<<9) + byteoff) ^ ((row & 7) << 4); } // 512B rows
__device__ __forceinline__ int swzW(int row, int byteoff){ return ((row<<6) + byteoff) ^ ((row & 7) << 4); } // 64B rows
__device__ __forceinline__ int swzG(int row, int byteoff){ return ((row<<7) + byteoff) ^ ((row & 7) << 4); } // 128B rows

// ---------------- fill ----------------
__global__ void fill_u32_kernel(unsigned* p, unsigned v, int n){
  int g = blockIdx.x*256 + threadIdx.x;
  if (g < n) p[g] = v;
}

// ---------------- weight prep ----------------
// Wcat[512][256] bf16 = [Wih | Whh]; bias = bih+bhh (f32); W1b = bf16(W1)
__global__ void prep_kernel(const float* __restrict__ Wih, const float* __restrict__ Whh,
                            const float* __restrict__ bih, const float* __restrict__ bhh,
                            const float* __restrict__ W1,
                            __bf16* __restrict__ Wcat, float* __restrict__ bias,
                            __bf16* __restrict__ W1b){
  int g = blockIdx.x*256 + threadIdx.x;
  if (g < 131072){
    int j = g >> 8, k = g & 255;
    float v = (k < 128) ? Wih[j*128 + k] : Whh[j*128 + (k-128)];
    Wcat[g] = (__bf16)v;
  } else if (g < 131584){
    int j = g - 131072;
    bias[j] = bih[j] + bhh[j];
  } else if (g < 164352){
    int q = g - 131584;
    W1b[q] = (__bf16)W1[q];
  }
}

// ---------------- gather + renorm (wave per row, 128-d rows) ----------------
// idxarr==nullptr -> row index = r+1 (for item_emb[1:])
__global__ void gather_renorm_kernel(const float* __restrict__ emb, const int* __restrict__ idxarr,
                                     __bf16* __restrict__ dst, int rows, int dstStride, int zeroFirst){
  int r = blockIdx.x*4 + (threadIdx.x >> 6);
  if (r >= rows) return;
  int lane = threadIdx.x & 63;
  int idx = idxarr ? idxarr[r] : (r + 1);
  float2 v = *(const float2*)(emb + (size_t)idx*128 + lane*2);
  float ss = v.x*v.x + v.y*v.y;
  #pragma unroll
  for (int m = 1; m < 64; m <<= 1) ss += __shfl_xor(ss, m);
  float scale = (ss > 1.f) ? (1.f/sqrtf(ss)) : 1.f;
  if (zeroFirst && idx == 0) scale = 0.f;
  __bf16* o = dst + (size_t)r*dstStride + lane*2;
  o[0] = (__bf16)(v.x*scale);
  o[1] = (__bf16)(v.y*scale);
}

// ---------------- persistent LSTM ----------------
// Block: 64 samples x all 20 steps. 512 threads = 8 waves (2M x 4N), wave tile 32x128.
// A LDS [64][256] bf16: cols 0:128 = renorm(item_emb[seq]) (gathered in-kernel), 128:256 = h.
// W streamed per 32-K panel into 32KB LDS region, aliased with gate-staging G[16][512] f32.
// c state in registers (16/thread). Gates computed via mfma 16x16x32 bf16, bias preloaded into acc.
__global__ __launch_bounds__(512, 2)
void lstm_kernel(const float* __restrict__ item_emb, const int* __restrict__ seqs,
                 const __bf16* __restrict__ Wcat, const float* __restrict__ bias,
                 const int* __restrict__ lens, __bf16* __restrict__ A1){
  __shared__ char lds[65536];
  char* Ab = lds;            // [64][256] bf16, swizzled, row stride 512B
  char* WG = lds + 32768;    // W panel [512][32] bf16 (swizzled) | G [16][512] f32
  float* Gf = (float*)WG;

  const int tid  = threadIdx.x;
  const int lane = tid & 63;
  const int wv   = tid >> 6;
  const int wm   = wv >> 2;        // 0..1 (M half)
  const int wn   = wv & 3;         // 0..3 (gate chunk: i,f,g,o)
  const int l15  = lane & 15;
  const int lq   = lane >> 4;      // 0..3
  const int n0   = blockIdx.x * 64;

  float breg[8];
  #pragma unroll
  for (int ni = 0; ni < 8; ++ni) breg[ni] = bias[wn*128 + ni*16 + l15];

  int lens_r[16];
  #pragma unroll
  for (int p = 0; p < 4; ++p)
    #pragma unroll
    for (int i = 0; i < 4; ++i)
      lens_r[p*4+i] = lens[n0 + p*16 + (tid>>7) + i*4];

  float c_reg[16];
  #pragma unroll
  for (int q = 0; q < 16; ++q) c_reg[q] = 0.f;

  // zero h half (h0 = 0)
  {
    const int4 z = {0,0,0,0};
    #pragma unroll
    for (int i = 0; i < 2; ++i){
      int c = tid + i*512;
      int m = c >> 4, kc = c & 15;
      *(int4*)(Ab + swzA(m, 256 + kc*16)) = z;
    }
  }

  for (int t = 0; t < 20; ++t){
    // ---- stage x_t: gather + renorm item_emb row, convert bf16, into A[:,0:128] ----
    {
      int m   = wv*8 + (lane>>3);       // 0..63
      int sub = lane & 7;               // 8 lanes per row, 16 floats each
      int idx = seqs[(n0+m)*20 + t];
      const float* src = item_emb + (size_t)idx*128 + sub*16;
      float4 v0 = *(const float4*)(src + 0);
      float4 v1 = *(const float4*)(src + 4);
      float4 v2 = *(const float4*)(src + 8);
      float4 v3 = *(const float4*)(src + 12);
      float ss = v0.x*v0.x + v0.y*v0.y + v0.z*v0.z + v0.w*v0.w
               + v1.x*v1.x + v1.y*v1.y + v1.z*v1.z + v1.w*v1.w
               + v2.x*v2.x + v2.y*v2.y + v2.z*v2.z + v2.w*v2.w
               + v3.x*v3.x + v3.y*v3.y + v3.z*v3.z + v3.w*v3.w;
      ss += __shfl_xor(ss, 1); ss += __shfl_xor(ss, 2); ss += __shfl_xor(ss, 4);
      float scale = (ss > 1.f) ? (1.f/sqrtf(ss)) : 1.f;
      if (idx == 0) scale = 0.f;
      union { __bf16 h[16]; int4 q[2]; } u;
      u.h[0]=(__bf16)(v0.x*scale); u.h[1]=(__bf16)(v0.y*scale); u.h[2]=(__bf16)(v0.z*scale); u.h[3]=(__bf16)(v0.w*scale);
      u.h[4]=(__bf16)(v1.x*scale); u.h[5]=(__bf16)(v1.y*scale); u.h[6]=(__bf16)(v1.z*scale); u.h[7]=(__bf16)(v1.w*scale);
      u.h[8]=(__bf16)(v2.x*scale); u.h[9]=(__bf16)(v2.y*scale); u.h[10]=(__bf16)(v2.z*scale); u.h[11]=(__bf16)(v2.w*scale);
      u.h[12]=(__bf16)(v3.x*scale); u.h[13]=(__bf16)(v3.y*scale); u.h[14]=(__bf16)(v3.z*scale); u.h[15]=(__bf16)(v3.w*scale);
      *(int4*)(Ab + swzA(m, sub*32))      = u.q[0];
      *(int4*)(Ab + swzA(m, sub*32 + 16)) = u.q[1];
    }

    // init acc with bias (gates = A @ Wcat^T + b)
    f32x4 acc[2][8];
    #pragma unroll
    for (int mi = 0; mi < 2; ++mi)
      #pragma unroll
      for (int ni = 0; ni < 8; ++ni){
        f32x4 a; a[0]=breg[ni]; a[1]=breg[ni]; a[2]=breg[ni]; a[3]=breg[ni];
        acc[mi][ni] = a;
      }

    // ---- K loop: 8 panels of K=32 ----
    for (int kk = 0; kk < 8; ++kk){
      __syncthreads();   // prev WG readers done; stage writes visible after next barrier
      #pragma unroll
      for (int i = 0; i < 4; ++i){
        int c = tid + i*512;
        int j = c >> 2, kc = c & 3;
        int4 v = *(const int4*)((const char*)Wcat + (size_t)j*512 + kk*64 + kc*16);
        *(int4*)(WG + swzW(j, kc*16)) = v;
      }
      __syncthreads();
      bf16x8 a0 = __builtin_bit_cast(bf16x8, *(const int4*)(Ab + swzA(wm*32 +      l15, kk*64 + lq*16)));
      bf16x8 a1 = __builtin_bit_cast(bf16x8, *(const int4*)(Ab + swzA(wm*32 + 16 + l15, kk*64 + lq*16)));
      #pragma unroll
      for (int ni = 0; ni < 8; ++ni){
        int j = wn*128 + ni*16 + l15;
        bf16x8 b = __builtin_bit_cast(bf16x8, *(const int4*)(WG + swzW(j, lq*16)));
        acc[0][ni] = __builtin_amdgcn_mfma_f32_16x16x32_bf16(a0, b, acc[0][ni], 0,0,0);
        acc[1][ni] = __builtin_amdgcn_mfma_f32_16x16x32_bf16(a1, b, acc[1][ni], 0,0,0);
      }
    }
    __syncthreads();   // all frag reads done -> G region safe

    // ---- cell update in 4 phases of 16 rows ----
    #pragma unroll
    for (int p = 0; p < 4; ++p){
      if (wm == (p >> 1)){
        const int mi = p & 1;
        #pragma unroll
        for (int ni = 0; ni < 8; ++ni)
          #pragma unroll
          for (int r = 0; r < 4; ++r)
            Gf[(lq*4 + r)*512 + wn*128 + ni*16 + l15] = acc[mi][ni][r];
      }
      __syncthreads();
      const int d = tid & 127;
      #pragma unroll
      for (int i = 0; i < 4; ++i){
        int mloc = (tid>>7) + i*4;
        int m  = p*16 + mloc;
        int ci = p*4 + i;
        float ig = Gf[mloc*512 +       d];
        float fg = Gf[mloc*512 + 128 + d];
        float gg = Gf[mloc*512 + 256 + d];
        float og = Gf[mloc*512 + 384 + d];
        float ii = sigmoidf_(ig), ff = sigmoidf_(fg);
        float gt = tanhf_(gg),    oo = sigmoidf_(og);
        float cn = ff*c_reg[ci] + ii*gt;
        float hv = oo*tanhf_(cn);
        if (t < lens_r[ci]){
          c_reg[ci] = cn;
          *(__bf16*)(Ab + swzA(m, 256 + d*2)) = (__bf16)hv;
        }
      }
      __syncthreads();
    }
  }

  // write hn -> A1[:,128:256]
  #pragma unroll
  for (int i = 0; i < 16; ++i){
    int idx = tid + i*512;
    int m = idx >> 7, d = idx & 127;
    __bf16 h = *(const __bf16*)(Ab + swzA(m, 256 + d*2));
    A1[(size_t)(n0+m)*256 + 128 + d] = h;
  }
}

// ---------------- generic bf16 GEMM: C[M][N] = A[M][K] @ B[N][K]^T, f32 out ----------------
// 128x128 tile, 4 waves (2x2), wave 64x64, BK=64. M must be multiple of 128; N bounds-checked.
template<int RELU>
__global__ __launch_bounds__(256, 2)
void gemm_bt_kernel(const __bf16* __restrict__ A, const __bf16* __restrict__ B,
                    float* __restrict__ C, int M, int N, int K){
  __shared__ char As[16384];
  __shared__ char Bs[16384];
  const int tid  = threadIdx.x;
  const int lane = tid & 63;
  const int wv   = tid >> 6;
  const int wmw  = wv >> 1, wnw = wv & 1;
  const int l15  = lane & 15, lq = lane >> 4;
  const int n0 = blockIdx.x * 128;
  const int m0 = blockIdx.y * 128;

  f32x4 acc[4][4];
  #pragma unroll
  for (int a = 0; a < 4; ++a)
    #pragma unroll
    for (int b = 0; b < 4; ++b){ f32x4 z; z[0]=0.f;z[1]=0.f;z[2]=0.f;z[3]=0.f; acc[a][b]=z; }

  const int nkb = K >> 6;
  for (int kb = 0; kb < nkb; ++kb){
    __syncthreads();
    #pragma unroll
    for (int i = 0; i < 4; ++i){
      int c = tid + i*256;
      int row = c >> 3, kc = c & 7;
      int4 va = *(const int4*)(A + (size_t)(m0+row)*K + kb*64 + kc*8);
      *(int4*)(As + swzG(row, kc*16)) = va;
      int4 vb = {0,0,0,0};
      if (n0 + row < N) vb = *(const int4*)(B + (size_t)(n0+row)*K + kb*64 + kc*8);
      *(int4*)(Bs + swzG(row, kc*16)) = vb;
    }
    __syncthreads();
    #pragma unroll
    for (int ks = 0; ks < 2; ++ks){
      bf16x8 af[4], bfr[4];
      #pragma unroll
      for (int mi = 0; mi < 4; ++mi)
        af[mi] = __builtin_bit_cast(bf16x8, *(const int4*)(As + swzG(wmw*64 + mi*16 + l15, ks*64 + lq*16)));
      #pragma unroll
      for (int ni = 0; ni < 4; ++ni)
        bfr[ni] = __builtin_bit_cast(bf16x8, *(const int4*)(Bs + swzG(wnw*64 + ni*16 + l15, ks*64 + lq*16)));
      #pragma unroll
      for (int mi = 0; mi < 4; ++mi)
        #pragma unroll
        for (int ni = 0; ni < 4; ++ni)
          acc[mi][ni] = __builtin_amdgcn_mfma_f32_16x16x32_bf16(af[mi], bfr[ni], acc[mi][ni], 0,0,0);
    }
  }
  #pragma unroll
  for (int mi = 0; mi < 4; ++mi){
    #pragma unroll
    for (int ni = 0; ni < 4; ++ni){
      int col = n0 + wnw*64 + ni*16 + l15;
      if (col < N){
        #pragma unroll
        for (int r = 0; r < 4; ++r){
          int row = m0 + wmw*64 + mi*16 + lq*4 + r;
          float v = acc[mi][ni][r];
          if (RELU) v = fmaxf(v, 0.f);
          C[(size_t)row*N + col] = v;
        }
      }
    }
  }
}

// ---------------- feat[cur_sidx] = hn[cur_sidx] ----------------
__global__ void set_cur_kernel(const __bf16* __restrict__ A1, const int* __restrict__ cur_sidx,
                               float* __restrict__ feat){
  int g = blockIdx.x*256 + threadIdx.x;   // 512*128
  int i = g >> 7, d = g & 127;
  int row = cur_sidx[i];
  feat[(size_t)row*128 + d] = (float)A1[(size_t)row*256 + 128 + d];
}

// ---------------- GAT ----------------
__global__ void gat_score_kernel(const float* __restrict__ feat, const int* __restrict__ src,
                                 const int* __restrict__ dst, const int* __restrict__ idxm,
                                 float* __restrict__ score, unsigned* __restrict__ mbuf, int E){
  int e = blockIdx.x*4 + (threadIdx.x >> 6);
  if (e >= E) return;
  int lane = threadIdx.x & 63;
  int de = dst[e];
  const float2 a = *(const float2*)(feat + (size_t)src[e]*128 + lane*2);
  const float2 b = *(const float2*)(feat + (size_t)idxm[de]*128 + lane*2);
  float s = a.x*b.x + a.y*b.y;
  #pragma unroll
  for (int m = 1; m < 64; m <<= 1) s += __shfl_xor(s, m);
  if (lane == 0){
    score[e] = s;
    atomicMax(mbuf + de, encf(s));
  }
}

__global__ void gat_expsum_kernel(const float* __restrict__ score, const int* __restrict__ dst,
                                  const unsigned* __restrict__ mbuf, float* __restrict__ wbuf,
                                  float* __restrict__ z, int E){
  int e = blockIdx.x*256 + threadIdx.x;
  if (e >= E) return;
  int de = dst[e];
  float w = __expf(score[e] - decf(mbuf[de]));
  wbuf[e] = w;
  atomicAdd(z + de, w);
}

__global__ void gat_agg_kernel(const float* __restrict__ feat, const int* __restrict__ src,
                               const int* __restrict__ dst, const float* __restrict__ wbuf,
                               float* __restrict__ agg, int E){
  int g = blockIdx.x*256 + threadIdx.x;
  int e = g >> 7, d = g & 127;
  if (e >= E) return;
  atomicAdd(agg + (size_t)dst[e]*128 + d, wbuf[e] * feat[(size_t)src[e]*128 + d]);
}

// out[v][:] = featPrev[idxm[v]][:] + relu((agg[v]/max(z,eps)) @ gW^T + gb)
__global__ void gat_out_kernel(const float* __restrict__ featPrev, const int* __restrict__ idxm,
                               const float* __restrict__ agg, const float* __restrict__ z,
                               const float* __restrict__ gW, const float* __restrict__ gb,
                               float* __restrict__ out, int V){
  __shared__ float arow[128];
  int v = blockIdx.x;
  int d = threadIdx.x;   // 128 threads
  float zi = 1.f / fmaxf(z[v], 1e-12f);
  arow[d] = agg[(size_t)v*128 + d] * zi;
  __syncthreads();
  float s = gb[d];
  #pragma unroll 4
  for (int k = 0; k < 128; ++k) s += arow[k] * gW[d*128 + k];
  out[(size_t)v*128 + d] = featPrev[(size_t)idxm[v]*128 + d] + fmaxf(s, 0.f);
}

// ---------------- sr = concat(cur, feat2) @ W2^T (f32), store bf16 ----------------
__global__ void sr_kernel(const __bf16* __restrict__ A1, const float* __restrict__ feat2,
                          const int* __restrict__ cur_sidx, const float* __restrict__ W2,
                          __bf16* __restrict__ srb){
  __shared__ float cat[256];
  int i = blockIdx.x;
  int j = threadIdx.x;   // 128 threads
  int row = cur_sidx[i];
  cat[j]       = (float)A1[(size_t)row*256 + 128 + j];
  cat[128 + j] = feat2[(size_t)i*128 + j];
  __syncthreads();
  float s = 0.f;
  #pragma unroll 4
  for (int k = 0; k < 256; ++k) s += cat[k] * W2[j*256 + k];
  srb[(size_t)i*128 + j] = (__bf16)s;
}

// ---------------- launch ----------------
extern "C" void kernel_launch(void* const* d_in, const int* in_sizes, int n_in,
                              void* d_out, int out_size, void* d_ws, size_t ws_size,
                              hipStream_t stream){
  const float* user_emb = (const float*)d_in[0];
  const float* item_emb = (const float*)d_in[1];
  const float* Wih = (const float*)d_in[2];
  const float* Whh = (const float*)d_in[3];
  const float* bih = (const float*)d_in[4];
  const float* bhh = (const float*)d_in[5];
  const float* W1  = (const float*)d_in[6];
  const float* gW0 = (const float*)d_in[7];
  const float* gb0 = (const float*)d_in[8];
  const float* gW1 = (const float*)d_in[9];
  const float* gb1 = (const float*)d_in[10];
  const float* W2  = (const float*)d_in[11];
  const int* uids = (const int*)d_in[12];
  const int* seqs = (const int*)d_in[13];
  const int* lens = (const int*)d_in[14];
  const int* cur_sidx = (const int*)d_in[15];
  const int* src0 = (const int*)d_in[16];
  const int* dst0 = (const int*)d_in[17];
  const int* idx0 = (const int*)d_in[18];
  const int* src1 = (const int*)d_in[19];
  const int* dst1 = (const int*)d_in[20];
  const int* idx1 = (const int*)d_in[21];
  float* out = (float*)d_out;

  char* ws = (char*)d_ws;
  size_t off = 0;
  auto alloc = [&](size_t bytes)->char* {
    char* p = ws + off;
    off += (bytes + 255) & ~((size_t)255);
    return p;
  };
  __bf16*   A1    = (__bf16*)  alloc(25600u*256*2);   // [lt | hn] bf16
  __bf16*   Wcat  = (__bf16*)  alloc(512u*256*2);
  float*    bias  = (float*)   alloc(512u*4);
  __bf16*   W1b   = (__bf16*)  alloc(128u*256*2);
  float*    feat  = (float*)   alloc(25600u*128*4);
  float*    sc0   = (float*)   alloc(25600u*4);
  float*    w0    = (float*)   alloc(25600u*4);
  unsigned* m0    = (unsigned*)alloc(2560u*4);
  float*    z0    = (float*)   alloc(2560u*4);
  float*    agg0  = (float*)   alloc(2560u*128*4);
  float*    feat1 = (float*)   alloc(2560u*128*4);
  float*    sc1   = (float*)   alloc(5120u*4);
  float*    w1    = (float*)   alloc(5120u*4);
  unsigned* m1    = (unsigned*)alloc(512u*4);
  float*    z1    = (float*)   alloc(512u*4);
  float*    agg1  = (float*)   alloc(512u*128*4);
  float*    feat2 = (float*)   alloc(512u*128*4);
  __bf16*   srb   = (__bf16*)  alloc(512u*128*2);
  __bf16*   itn   = (__bf16*)  alloc(50000u*128*2);

  // prep + init
  prep_kernel<<<642, 256, 0, stream>>>(Wih, Whh, bih, bhh, W1, Wcat, bias, W1b);
  fill_u32_kernel<<<10,   256, 0, stream>>>((unsigned*)z0,   0u, 2560);
  fill_u32_kernel<<<1280, 256, 0, stream>>>((unsigned*)agg0, 0u, 327680);
  fill_u32_kernel<<<10,   256, 0, stream>>>(m0, 0x00800000u, 2560);   // enc(-FLT_MAX)
  fill_u32_kernel<<<2,    256, 0, stream>>>((unsigned*)z1,   0u, 512);
  fill_u32_kernel<<<256,  256, 0, stream>>>((unsigned*)agg1, 0u, 65536);
  fill_u32_kernel<<<2,    256, 0, stream>>>(m1, 0x00800000u, 512);

  // long_term = renorm(user_emb[uids]) -> A1[:,0:128]
  gather_renorm_kernel<<<6400, 256, 0, stream>>>(user_emb, uids, A1, 25600, 256, 0);

  // LSTM (gathers + renorms item_emb[seqs] in-kernel); hn -> A1[:,128:256]
  lstm_kernel<<<400, 512, 0, stream>>>(item_emb, seqs, Wcat, bias, lens, A1);

  // feat = relu(A1 @ W1^T)
  gemm_bt_kernel<1><<<dim3(1, 200), 256, 0, stream>>>(A1, W1b, feat, 25600, 128, 256);
  set_cur_kernel<<<256, 256, 0, stream>>>(A1, cur_sidx, feat);

  // GAT layer 0
  gat_score_kernel <<<6400, 256, 0, stream>>>(feat, src0, dst0, idx0, sc0, m0, 25600);
  gat_expsum_kernel<<<100,  256, 0, stream>>>(sc0, dst0, m0, w0, z0, 25600);
  gat_agg_kernel   <<<12800,256, 0, stream>>>(feat, src0, dst0, w0, agg0, 25600);
  gat_out_kernel   <<<2560, 128, 0, stream>>>(feat, idx0, agg0, z0, gW0, gb0, feat1, 2560);

  // GAT layer 1
  gat_score_kernel <<<1280, 256, 0, stream>>>(feat1, src1, dst1, idx1, sc1, m1, 5120);
  gat_expsum_kernel<<<20,   256, 0, stream>>>(sc1, dst1, m1, w1, z1, 5120);
  gat_agg_kernel   <<<2560, 256, 0, stream>>>(feat1, src1, dst1, w1, agg1, 5120);
  gat_out_kernel   <<<512,  128, 0, stream>>>(feat1, idx1, agg1, z1, gW1, gb1, feat2, 512);

  // sr = concat(cur, feat2) @ W2^T  (bf16 out for logits GEMM)
  sr_kernel<<<512, 128, 0, stream>>>(A1, feat2, cur_sidx, W2, srb);

  // renorm(item_emb[1:]) -> bf16
  gather_renorm_kernel<<<12500, 256, 0, stream>>>(item_emb, nullptr, itn, 50000, 128, 0);

  // logits = srb @ itn^T
  gemm_bt_kernel<0><<<dim3(391, 4), 256, 0, stream>>>(srb, itn, out, 512, 50000, 128);
}

// Round 2
// 514.236 us; speedup vs baseline: 2.2757x; 2.2757x over previous
//
#include <hip/hip_runtime.h>
#include <hip/hip_bf16.h>

typedef __bf16 bf16x8 __attribute__((ext_vector_type(8)));
typedef float  f32x4  __attribute__((ext_vector_type(4)));

__device__ __forceinline__ float sigmoidf_(float x){ return 1.f/(1.f+__expf(-x)); }
__device__ __forceinline__ float tanhf_(float x){
  float ax = fabsf(x);
  float e = __expf(-2.f*ax);
  float t = (1.f - e)/(1.f + e);
  return copysignf(t, x);
}

// float <-> order-preserving unsigned for atomicMax on floats
__device__ __forceinline__ unsigned encf(float f){
  unsigned u = __float_as_uint(f);
  return (u & 0x80000000u) ? ~u : (u | 0x80000000u);
}
__device__ __forceinline__ float decf(unsigned u){
  return __uint_as_float((u & 0x80000000u) ? (u ^ 0x80000000u) : ~u);
}

// LDS swizzles: XOR row-low-bits into 16B-slot bits (G4 fix for power-of-2 row strides)
__device__ __forceinline__ int swzA(int row, int byteoff){ return ((row<<9) + byteoff) ^ ((row & 7) << 4); } // 512B rows
__device__ __forceinline__ int swzG(int row, int byteoff){ return ((row<<7) + byteoff) ^ ((row & 7) << 4); } // 128B rows

// ---------------- fill ----------------
__global__ void fill_u32_kernel(unsigned* p, unsigned v, int n){
  int g = blockIdx.x*256 + threadIdx.x;
  if (g < n) p[g] = v;
}

// ---------------- weight prep ----------------
// Wcat[512][256] bf16 = [Wih | Whh]; bias = bih+bhh (f32); W1b = bf16(W1)
__global__ void prep_kernel(const float* __restrict__ Wih, const float* __restrict__ Whh,
                            const float* __restrict__ bih, const float* __restrict__ bhh,
                            const float* __restrict__ W1,
                            __bf16* __restrict__ Wcat, float* __restrict__ bias,
                            __bf16* __restrict__ W1b){
  int g = blockIdx.x*256 + threadIdx.x;
  if (g < 131072){
    int j = g >> 8, k = g & 255;
    float v = (k < 128) ? Wih[j*128 + k] : Whh[j*128 + (k-128)];
    Wcat[g] = (__bf16)v;
  } else if (g < 131584){
    int j = g - 131072;
    bias[j] = bih[j] + bhh[j];
  } else if (g < 164352){
    int q = g - 131584;
    W1b[q] = (__bf16)W1[q];
  }
}

// ---------------- gather + renorm (wave per row, 128-d rows) ----------------
// idxarr==nullptr -> row index = r+1 (for item_emb[1:])
__global__ void gather_renorm_kernel(const float* __restrict__ emb, const int* __restrict__ idxarr,
                                     __bf16* __restrict__ dst, int rows, int dstStride, int zeroFirst){
  int r = blockIdx.x*4 + (threadIdx.x >> 6);
  if (r >= rows) return;
  int lane = threadIdx.x & 63;
  int idx = idxarr ? idxarr[r] : (r + 1);
  float2 v = *(const float2*)(emb + (size_t)idx*128 + lane*2);
  float ss = v.x*v.x + v.y*v.y;
  #pragma unroll
  for (int m = 1; m < 64; m <<= 1) ss += __shfl_xor(ss, m);
  float scale = (ss > 1.f) ? (1.f/sqrtf(ss)) : 1.f;
  if (zeroFirst && idx == 0) scale = 0.f;
  __bf16* o = dst + (size_t)r*dstStride + lane*2;
  o[0] = (__bf16)(v.x*scale);
  o[1] = (__bf16)(v.y*scale);
}

// ---------------- persistent LSTM, W register-resident ----------------
// Block: 32 samples x all 20 steps. 512 threads = 8 waves.
// Swapped MFMA: gates^T[gate_row][sample] = mfma(A=W rows, B=sample rows).
// Wave wv owns gate rows {g*128 + wv*16 .. +15, g=0..3} -> each lane ends up with
// i,f,g,o for its (sample, dim) pairs IN REGISTERS -> cell update has no LDS round trip.
// A-tile LDS [32][256] bf16 (x_t | h_t), swizzled. 2 barriers/step.
// x_{t+1} gather prefetched into regs during step t's MFMA phase (T14).
__global__ __launch_bounds__(512, 2)
void lstm_kernel(const float* __restrict__ item_emb, const int* __restrict__ seqs,
                 const __bf16* __restrict__ Wcat, const float* __restrict__ bias,
                 const int* __restrict__ lens, __bf16* __restrict__ A1){
  __shared__ char Ab[16384];   // [32][256] bf16, row stride 512B, swizzled

  const int tid  = threadIdx.x;
  const int lane = tid & 63;
  const int wv   = tid >> 6;   // 0..7 : dim group wv*16..wv*16+15
  const int l15  = lane & 15;
  const int lq   = lane >> 4;  // 0..3
  const int n0   = blockIdx.x * 32;

  // ---- W fragments, register-resident for the whole kernel ----
  // w[gi][kk]: A-frag for gate rows gi*128 + wv*16 + l15, k = kk*32 + lq*8 .. +8
  bf16x8 w[4][8];
  #pragma unroll
  for (int gi = 0; gi < 4; ++gi){
    const __bf16* wp = Wcat + (size_t)(gi*128 + wv*16 + l15)*256 + lq*8;
    #pragma unroll
    for (int kk = 0; kk < 8; ++kk)
      w[gi][kk] = __builtin_bit_cast(bf16x8, *(const int4*)(wp + kk*32));
  }
  // bias for this lane's dims: d = wv*16 + lq*4 + r
  float bb[4][4];
  #pragma unroll
  for (int gi = 0; gi < 4; ++gi)
    #pragma unroll
    for (int r = 0; r < 4; ++r)
      bb[gi][r] = bias[gi*128 + wv*16 + lq*4 + r];

  const int ln0 = lens[n0 + l15];
  const int ln1 = lens[n0 + 16 + l15];

  float c0[4], c1[4];
  #pragma unroll
  for (int r = 0; r < 4; ++r){ c0[r] = 0.f; c1[r] = 0.f; }

  // ---- x staging geometry: thread handles row (tid>>4), 8 dims at (tid&15)*8 ----
  const int xrow = tid >> 4;          // 0..31
  const int xc   = (tid & 15) * 8;    // dim offset

  // zero h half
  {
    const int4 z = {0,0,0,0};
    *(int4*)(Ab + swzA(xrow, 256 + (tid & 15)*16)) = z;
  }

  // gather x_0
  int idx_cur = seqs[(n0 + xrow)*20 + 0];
  float xr[8];
  {
    const float* sp = item_emb + (size_t)idx_cur*128 + xc;
    float4 a = *(const float4*)(sp);
    float4 b = *(const float4*)(sp + 4);
    xr[0]=a.x; xr[1]=a.y; xr[2]=a.z; xr[3]=a.w;
    xr[4]=b.x; xr[5]=b.y; xr[6]=b.z; xr[7]=b.w;
  }
  // renorm + write x_0
  {
    float ss = 0.f;
    #pragma unroll
    for (int j = 0; j < 8; ++j) ss += xr[j]*xr[j];
    ss += __shfl_xor(ss, 1); ss += __shfl_xor(ss, 2);
    ss += __shfl_xor(ss, 4); ss += __shfl_xor(ss, 8);
    float scale = (ss > 1.f) ? (1.f/sqrtf(ss)) : 1.f;
    if (idx_cur == 0) scale = 0.f;
    union { __bf16 h[8]; int4 q; } u;
    #pragma unroll
    for (int j = 0; j < 8; ++j) u.h[j] = (__bf16)(xr[j]*scale);
    *(int4*)(Ab + swzA(xrow, (tid & 15)*16)) = u.q;
  }
  int idx_next = seqs[(n0 + xrow)*20 + 1];   // seq idx prefetch (t+1)
  __syncthreads();

  for (int t = 0; t < 20; ++t){
    // ---- prefetch x_{t+1} into regs (loads fly during MFMA phase) ----
    float xn[8];
    int idx_use = idx_next;
    if (t < 19){
      const float* sp = item_emb + (size_t)idx_use*128 + xc;
      float4 a = *(const float4*)(sp);
      float4 b = *(const float4*)(sp + 4);
      xn[0]=a.x; xn[1]=a.y; xn[2]=a.z; xn[3]=a.w;
      xn[4]=b.x; xn[5]=b.y; xn[6]=b.z; xn[7]=b.w;
    }
    if (t < 18) idx_next = seqs[(n0 + xrow)*20 + t + 2];

    // ---- gates^T = W @ [x|h]^T : acc[mi][gi], D[row=dim(lq*4+r)][col=sample(l15)] ----
    f32x4 acc[2][4];
    #pragma unroll
    for (int mi = 0; mi < 2; ++mi)
      #pragma unroll
      for (int gi = 0; gi < 4; ++gi){ f32x4 z; z[0]=0.f;z[1]=0.f;z[2]=0.f;z[3]=0.f; acc[mi][gi]=z; }

    #pragma unroll
    for (int kk = 0; kk < 8; ++kk){
      bf16x8 b0 = __builtin_bit_cast(bf16x8, *(const int4*)(Ab + swzA(l15,      kk*64 + lq*16)));
      bf16x8 b1 = __builtin_bit_cast(bf16x8, *(const int4*)(Ab + swzA(16 + l15, kk*64 + lq*16)));
      #pragma unroll
      for (int gi = 0; gi < 4; ++gi){
        acc[0][gi] = __builtin_amdgcn_mfma_f32_16x16x32_bf16(w[gi][kk], b0, acc[0][gi], 0,0,0);
        acc[1][gi] = __builtin_amdgcn_mfma_f32_16x16x32_bf16(w[gi][kk], b1, acc[1][gi], 0,0,0);
      }
    }

    // ---- cell update fully in registers ----
    // lane holds gates for samples {l15, 16+l15}, dims d = wv*16 + lq*4 + r
    float hv0[4], hv1[4];
    const bool up0 = (t < ln0), up1 = (t < ln1);
    #pragma unroll
    for (int r = 0; r < 4; ++r){
      {
        float ig = acc[0][0][r] + bb[0][r];
        float fg = acc[0][1][r] + bb[1][r];
        float gg = acc[0][2][r] + bb[2][r];
        float og = acc[0][3][r] + bb[3][r];
        float cn = sigmoidf_(fg)*c0[r] + sigmoidf_(ig)*tanhf_(gg);
        hv0[r] = sigmoidf_(og)*tanhf_(cn);
        if (up0) c0[r] = cn;
      }
      {
        float ig = acc[1][0][r] + bb[0][r];
        float fg = acc[1][1][r] + bb[1][r];
        float gg = acc[1][2][r] + bb[2][r];
        float og = acc[1][3][r] + bb[3][r];
        float cn = sigmoidf_(fg)*c1[r] + sigmoidf_(ig)*tanhf_(gg);
        hv1[r] = sigmoidf_(og)*tanhf_(cn);
        if (up1) c1[r] = cn;
      }
    }

    __syncthreads();   // all waves done reading A-tile

    // ---- write h_{t+1} (masked lanes keep old h by not storing) ----
    #pragma unroll
    for (int r = 0; r < 4; ++r){
      int d = wv*16 + lq*4 + r;
      if (up0) *(__bf16*)(Ab + swzA(l15,      256 + d*2)) = (__bf16)hv0[r];
      if (up1) *(__bf16*)(Ab + swzA(16 + l15, 256 + d*2)) = (__bf16)hv1[r];
    }

    // ---- renorm + write x_{t+1} ----
    if (t < 19){
      float ss = 0.f;
      #pragma unroll
      for (int j = 0; j < 8; ++j) ss += xn[j]*xn[j];
      ss += __shfl_xor(ss, 1); ss += __shfl_xor(ss, 2);
      ss += __shfl_xor(ss, 4); ss += __shfl_xor(ss, 8);
      float scale = (ss > 1.f) ? (1.f/sqrtf(ss)) : 1.f;
      if (idx_use == 0) scale = 0.f;
      union { __bf16 h[8]; int4 q; } u;
      #pragma unroll
      for (int j = 0; j < 8; ++j) u.h[j] = (__bf16)(xn[j]*scale);
      *(int4*)(Ab + swzA(xrow, (tid & 15)*16)) = u.q;
    }

    __syncthreads();   // A-tile ready for step t+1
  }

  // ---- export hn -> A1[:,128:256] ----
  {
    int4 hq = *(const int4*)(Ab + swzA(xrow, 256 + (tid & 15)*16));
    *(int4*)(A1 + (size_t)(n0 + xrow)*256 + 128 + xc) = hq;
  }
}

// ---------------- generic bf16 GEMM: C[M][N] = A[M][K] @ B[N][K]^T, f32 out ----------------
// 128x128 tile, 4 waves (2x2), wave 64x64, BK=64. M must be multiple of 128; N bounds-checked.
template<int RELU>
__global__ __launch_bounds__(256, 2)
void gemm_bt_kernel(const __bf16* __restrict__ A, const __bf16* __restrict__ B,
                    float* __restrict__ C, int M, int N, int K){
  __shared__ char As[16384];
  __shared__ char Bs[16384];
  const int tid  = threadIdx.x;
  const int lane = tid & 63;
  const int wv   = tid >> 6;
  const int wmw  = wv >> 1, wnw = wv & 1;
  const int l15  = lane & 15, lq = lane >> 4;
  const int n0 = blockIdx.x * 128;
  const int m0 = blockIdx.y * 128;

  f32x4 acc[4][4];
  #pragma unroll
  for (int a = 0; a < 4; ++a)
    #pragma unroll
    for (int b = 0; b < 4; ++b){ f32x4 z; z[0]=0.f;z[1]=0.f;z[2]=0.f;z[3]=0.f; acc[a][b]=z; }

  const int nkb = K >> 6;
  for (int kb = 0; kb < nkb; ++kb){
    __syncthreads();
    #pragma unroll
    for (int i = 0; i < 4; ++i){
      int c = tid + i*256;
      int row = c >> 3, kc = c & 7;
      int4 va = *(const int4*)(A + (size_t)(m0+row)*K + kb*64 + kc*8);
      *(int4*)(As + swzG(row, kc*16)) = va;
      int4 vb = {0,0,0,0};
      if (n0 + row < N) vb = *(const int4*)(B + (size_t)(n0+row)*K + kb*64 + kc*8);
      *(int4*)(Bs + swzG(row, kc*16)) = vb;
    }
    __syncthreads();
    #pragma unroll
    for (int ks = 0; ks < 2; ++ks){
      bf16x8 af[4], bfr[4];
      #pragma unroll
      for (int mi = 0; mi < 4; ++mi)
        af[mi] = __builtin_bit_cast(bf16x8, *(const int4*)(As + swzG(wmw*64 + mi*16 + l15, ks*64 + lq*16)));
      #pragma unroll
      for (int ni = 0; ni < 4; ++ni)
        bfr[ni] = __builtin_bit_cast(bf16x8, *(const int4*)(Bs + swzG(wnw*64 + ni*16 + l15, ks*64 + lq*16)));
      #pragma unroll
      for (int mi = 0; mi < 4; ++mi)
        #pragma unroll
        for (int ni = 0; ni < 4; ++ni)
          acc[mi][ni] = __builtin_amdgcn_mfma_f32_16x16x32_bf16(af[mi], bfr[ni], acc[mi][ni], 0,0,0);
    }
  }
  #pragma unroll
  for (int mi = 0; mi < 4; ++mi){
    #pragma unroll
    for (int ni = 0; ni < 4; ++ni){
      int col = n0 + wnw*64 + ni*16 + l15;
      if (col < N){
        #pragma unroll
        for (int r = 0; r < 4; ++r){
          int row = m0 + wmw*64 + mi*16 + lq*4 + r;
          float v = acc[mi][ni][r];
          if (RELU) v = fmaxf(v, 0.f);
          C[(size_t)row*N + col] = v;
        }
      }
    }
  }
}

// ---------------- feat[cur_sidx] = hn[cur_sidx] ----------------
__global__ void set_cur_kernel(const __bf16* __restrict__ A1, const int* __restrict__ cur_sidx,
                               float* __restrict__ feat){
  int g = blockIdx.x*256 + threadIdx.x;   // 512*128
  int i = g >> 7, d = g & 127;
  int row = cur_sidx[i];
  feat[(size_t)row*128 + d] = (float)A1[(size_t)row*256 + 128 + d];
}

// ---------------- GAT ----------------
__global__ void gat_score_kernel(const float* __restrict__ feat, const int* __restrict__ src,
                                 const int* __restrict__ dst, const int* __restrict__ idxm,
                                 float* __restrict__ score, unsigned* __restrict__ mbuf, int E){
  int e = blockIdx.x*4 + (threadIdx.x >> 6);
  if (e >= E) return;
  int lane = threadIdx.x & 63;
  int de = dst[e];
  const float2 a = *(const float2*)(feat + (size_t)src[e]*128 + lane*2);
  const float2 b = *(const float2*)(feat + (size_t)idxm[de]*128 + lane*2);
  float s = a.x*b.x + a.y*b.y;
  #pragma unroll
  for (int m = 1; m < 64; m <<= 1) s += __shfl_xor(s, m);
  if (lane == 0){
    score[e] = s;
    atomicMax(mbuf + de, encf(s));
  }
}

__global__ void gat_expsum_kernel(const float* __restrict__ score, const int* __restrict__ dst,
                                  const unsigned* __restrict__ mbuf, float* __restrict__ wbuf,
                                  float* __restrict__ z, int E){
  int e = blockIdx.x*256 + threadIdx.x;
  if (e >= E) return;
  int de = dst[e];
  float w = __expf(score[e] - decf(mbuf[de]));
  wbuf[e] = w;
  atomicAdd(z + de, w);
}

__global__ void gat_agg_kernel(const float* __restrict__ feat, const int* __restrict__ src,
                               const int* __restrict__ dst, const float* __restrict__ wbuf,
                               float* __restrict__ agg, int E){
  int g = blockIdx.x*256 + threadIdx.x;
  int e = g >> 7, d = g & 127;
  if (e >= E) return;
  atomicAdd(agg + (size_t)dst[e]*128 + d, wbuf[e] * feat[(size_t)src[e]*128 + d]);
}

// out[v][:] = featPrev[idxm[v]][:] + relu((agg[v]/max(z,eps)) @ gW^T + gb)
__global__ void gat_out_kernel(const float* __restrict__ featPrev, const int* __restrict__ idxm,
                               const float* __restrict__ agg, const float* __restrict__ z,
                               const float* __restrict__ gW, const float* __restrict__ gb,
                               float* __restrict__ out, int V){
  __shared__ float arow[128];
  int v = blockIdx.x;
  int d = threadIdx.x;   // 128 threads
  float zi = 1.f / fmaxf(z[v], 1e-12f);
  arow[d] = agg[(size_t)v*128 + d] * zi;
  __syncthreads();
  float s = gb[d];
  #pragma unroll 4
  for (int k = 0; k < 128; ++k) s += arow[k] * gW[d*128 + k];
  out[(size_t)v*128 + d] = featPrev[(size_t)idxm[v]*128 + d] + fmaxf(s, 0.f);
}

// ---------------- sr = concat(cur, feat2) @ W2^T (f32), store bf16 ----------------
__global__ void sr_kernel(const __bf16* __restrict__ A1, const float* __restrict__ feat2,
                          const int* __restrict__ cur_sidx, const float* __restrict__ W2,
                          __bf16* __restrict__ srb){
  __shared__ float cat[256];
  int i = blockIdx.x;
  int j = threadIdx.x;   // 128 threads
  int row = cur_sidx[i];
  cat[j]       = (float)A1[(size_t)row*256 + 128 + j];
  cat[128 + j] = feat2[(size_t)i*128 + j];
  __syncthreads();
  float s = 0.f;
  #pragma unroll 4
  for (int k = 0; k < 256; ++k) s += cat[k] * W2[j*256 + k];
  srb[(size_t)i*128 + j] = (__bf16)s;
}

// ---------------- launch ----------------
extern "C" void kernel_launch(void* const* d_in, const int* in_sizes, int n_in,
                              void* d_out, int out_size, void* d_ws, size_t ws_size,
                              hipStream_t stream){
  const float* user_emb = (const float*)d_in[0];
  const float* item_emb = (const float*)d_in[1];
  const float* Wih = (const float*)d_in[2];
  const float* Whh = (const float*)d_in[3];
  const float* bih = (const float*)d_in[4];
  const float* bhh = (const float*)d_in[5];
  const float* W1  = (const float*)d_in[6];
  const float* gW0 = (const float*)d_in[7];
  const float* gb0 = (const float*)d_in[8];
  const float* gW1 = (const float*)d_in[9];
  const float* gb1 = (const float*)d_in[10];
  const float* W2  = (const float*)d_in[11];
  const int* uids = (const int*)d_in[12];
  const int* seqs = (const int*)d_in[13];
  const int* lens = (const int*)d_in[14];
  const int* cur_sidx = (const int*)d_in[15];
  const int* src0 = (const int*)d_in[16];
  const int* dst0 = (const int*)d_in[17];
  const int* idx0 = (const int*)d_in[18];
  const int* src1 = (const int*)d_in[19];
  const int* dst1 = (const int*)d_in[20];
  const int* idx1 = (const int*)d_in[21];
  float* out = (float*)d_out;

  char* ws = (char*)d_ws;
  size_t off = 0;
  auto alloc = [&](size_t bytes)->char* {
    char* p = ws + off;
    off += (bytes + 255) & ~((size_t)255);
    return p;
  };
  __bf16*   A1    = (__bf16*)  alloc(25600u*256*2);   // [lt | hn] bf16
  __bf16*   Wcat  = (__bf16*)  alloc(512u*256*2);
  float*    bias  = (float*)   alloc(512u*4);
  __bf16*   W1b   = (__bf16*)  alloc(128u*256*2);
  float*    feat  = (float*)   alloc(25600u*128*4);
  float*    sc0   = (float*)   alloc(25600u*4);
  float*    w0    = (float*)   alloc(25600u*4);
  unsigned* m0    = (unsigned*)alloc(2560u*4);
  float*    z0    = (float*)   alloc(2560u*4);
  float*    agg0  = (float*)   alloc(2560u*128*4);
  float*    feat1 = (float*)   alloc(2560u*128*4);
  float*    sc1   = (float*)   alloc(5120u*4);
  float*    w1    = (float*)   alloc(5120u*4);
  unsigned* m1    = (unsigned*)alloc(512u*4);
  float*    z1    = (float*)   alloc(512u*4);
  float*    agg1  = (float*)   alloc(512u*128*4);
  float*    feat2 = (float*)   alloc(512u*128*4);
  __bf16*   srb   = (__bf16*)  alloc(512u*128*2);
  __bf16*   itn   = (__bf16*)  alloc(50000u*128*2);

  // prep + init
  prep_kernel<<<642, 256, 0, stream>>>(Wih, Whh, bih, bhh, W1, Wcat, bias, W1b);
  fill_u32_kernel<<<10,   256, 0, stream>>>((unsigned*)z0,   0u, 2560);
  fill_u32_kernel<<<1280, 256, 0, stream>>>((unsigned*)agg0, 0u, 327680);
  fill_u32_kernel<<<10,   256, 0, stream>>>(m0, 0x00800000u, 2560);   // enc(-FLT_MAX)
  fill_u32_kernel<<<2,    256, 0, stream>>>((unsigned*)z1,   0u, 512);
  fill_u32_kernel<<<256,  256, 0, stream>>>((unsigned*)agg1, 0u, 65536);
  fill_u32_kernel<<<2,    256, 0, stream>>>(m1, 0x00800000u, 512);

  // long_term = renorm(user_emb[uids]) -> A1[:,0:128]
  gather_renorm_kernel<<<6400, 256, 0, stream>>>(user_emb, uids, A1, 25600, 256, 0);

  // LSTM (gathers + renorms item_emb[seqs] in-kernel); hn -> A1[:,128:256]
  lstm_kernel<<<800, 512, 0, stream>>>(item_emb, seqs, Wcat, bias, lens, A1);

  // feat = relu(A1 @ W1^T)
  gemm_bt_kernel<1><<<dim3(1, 200), 256, 0, stream>>>(A1, W1b, feat, 25600, 128, 256);
  set_cur_kernel<<<256, 256, 0, stream>>>(A1, cur_sidx, feat);

  // GAT layer 0
  gat_score_kernel <<<6400, 256, 0, stream>>>(feat, src0, dst0, idx0, sc0, m0, 25600);
  gat_expsum_kernel<<<100,  256, 0, stream>>>(sc0, dst0, m0, w0, z0, 25600);
  gat_agg_kernel   <<<12800,256, 0, stream>>>(feat, src0, dst0, w0, agg0, 25600);
  gat_out_kernel   <<<2560, 128, 0, stream>>>(feat, idx0, agg0, z0, gW0, gb0, feat1, 2560);

  // GAT layer 1
  gat_score_kernel <<<1280, 256, 0, stream>>>(feat1, src1, dst1, idx1, sc1, m1, 5120);
  gat_expsum_kernel<<<20,   256, 0, stream>>>(sc1, dst1, m1, w1, z1, 5120);
  gat_agg_kernel   <<<2560, 256, 0, stream>>>(feat1, src1, dst1, w1, agg1, 5120);
  gat_out_kernel   <<<512,  128, 0, stream>>>(feat1, idx1, agg1, z1, gW1, gb1, feat2, 512);

  // sr = concat(cur, feat2) @ W2^T  (bf16 out for logits GEMM)
  sr_kernel<<<512, 128, 0, stream>>>(A1, feat2, cur_sidx, W2, srb);

  // renorm(item_emb[1:]) -> bf16
  gather_renorm_kernel<<<12500, 256, 0, stream>>>(item_emb, nullptr, itn, 50000, 128, 0);

  // logits = srb @ itn^T
  gemm_bt_kernel<0><<<dim3(391, 4), 256, 0, stream>>>(srb, itn, out, 512, 50000, 128);
}